// Round 6
// baseline (225.593 us; speedup 1.0000x reference)
//
#include <hip/hip_runtime.h>
#include <math.h>

namespace {
constexpr int NIN   = 32;
constexpr int H_    = 14;
constexpr int CIN   = 8;
constexpr int C_    = 32;
constexpr int COUT  = 16;
constexpr int R_    = 288;
constexpr int W_    = 12;
constexpr int NITER = 3;
constexpr int CH    = 32;              // r per chunk
constexpr int NCH   = 9;               // 288/32
constexpr size_t XSUB = (size_t)NIN * H_ * H_ * CIN;   // x stride per batch elem
}

typedef unsigned int u32;
typedef const __attribute__((address_space(1))) u32* as1_u32p;
typedef __attribute__((address_space(3))) u32* as3_u32p;

__device__ __forceinline__ void async_copy16(const void* g, void* l) {
    __builtin_amdgcn_global_load_lds((as1_u32p)g, (as3_u32p)l, 16, 0, 0);
}
__device__ __forceinline__ float dot4(const float4 a, const float4 b) {
    return fmaf(a.x, b.x, fmaf(a.y, b.y, fmaf(a.z, b.z, a.w * b.w)));
}
// VALU-pipe cross-lane ops (DPP) — keep traffic off the DS pipe.
__device__ __forceinline__ float dpp_add_xor1(float v) {
    int t = __builtin_amdgcn_update_dpp(0, __float_as_int(v), 0xB1, 0xF, 0xF, true);
    return v + __int_as_float(t);
}
__device__ __forceinline__ float dpp_add_xor2(float v) {
    int t = __builtin_amdgcn_update_dpp(0, __float_as_int(v), 0x4E, 0xF, 0xF, true);
    return v + __int_as_float(t);
}
__device__ __forceinline__ float dpp_add_shr4(float v) {
    int t = __builtin_amdgcn_update_dpp(0, __float_as_int(v), 0x114, 0xF, 0xF, true);
    return v + __int_as_float(t);
}
__device__ __forceinline__ float dpp_add_shr8(float v) {
    int t = __builtin_amdgcn_update_dpp(0, __float_as_int(v), 0x118, 0xF, 0xF, true);
    return v + __int_as_float(t);
}

// R18 = R17 (XCD swizzle, FETCH 24.5->7.9 MB, kept) + x-path instruction diet.
// Diagnosis: VALUBusy*wall = 102 us busy vs ~17 us useful-FMA issue — the
// kernel is overhead-issue-bound, not delivery-bound (R17 proved locality
// fix doesn't move wall). Changes, arithmetic bit-identical:
//  (a) x-direct loads (R11 retry, safe now that x is L2-resident per XCD):
//      each thread loads both subs' 8 x-floats via 4 global_load_dwordx4
//      from wave-uniform SGPR bases + one shared voffset (offset:0/16).
//      Deletes all 16 DPP broadcasts per chunk. 4x og-redundant loads hit
//      L2 (~200cy), absorbed by prefetch distance-1 within the phase.
//  (b) LDS offset LUT: vofs[r] built once per block (288 ints, 1.2 KB),
//      read into 9 VGPRs in the prologue (conflict-free ds_read_b32:
//      bank = cr). Deletes the per-chunk r/9, rem/3 magic-div chain.
//  Per-chunk x cost: ~6 issue slots vs ~27. VGPR ~110 (acc 72 + x 32 +
//  vofs 9), same 128 bucket -> occupancy cap unchanged.
// Lessons: 256-thr blocks (R6/R10); no forced waves/EU (R4); zero-VGPR
// global_load_lds + plain __syncthreads (R7; counted-vmcnt 0-for-3:
// R14/R16); priors fp32 (R2); residency pinned at 0.62 x min(LDS-cap,
// 16 waves), VGPR>=72 closes that book (R13-R16); all-wave redundant
// squash (R15); XCD swizzle cuts HBM 3x, keep (R17).
__global__ __launch_bounds__(256)
void caps_routeC(const float* __restrict__ x,
                 const float* __restrict__ rw,
                 float* __restrict__ out)
{
    const int tid = threadIdx.x;
    // XCD-aware decode (R17): xcd = hw%8; XCD k owns groups 8k..8k+7.
    const int hw    = blockIdx.x;
    const int xcd   = hw & 7;
    const int local = hw >> 3;          // 0..1151
    const int pq    = local % 144;
    const int gl    = local / 144;      // 0..7
    const int grp   = xcd * 8 + gl;     // = y*32 + c
    const int yb    = grp >> 5;         // batch-quad index 0..1
    const int c     = grp & 31;
    const int p  = pq / W_;
    const int q  = pq % W_;
    const int b0 = yb * 4;

    __shared__ float4 wbuf[2][1024];     // [buf][i(8)][cr(32)][og(4)] 16 KB each
    __shared__ float  sRed[2][4][2][16]; // [parity][wave][local sub][o]
    __shared__ float  redE[2][4][2];     // [parity][wave][local sub]
    __shared__ int    lutX[R_];          // per-block x byte-offsets (p,q folded)

    const int og   = tid & 3;
    const int rl   = tid >> 2;     // 0..63
    const int cr   = rl & 31;      // chunk-local r
    const int sh   = rl >> 5;      // wave-uniform: waves 0,1 -> subs 0,1; 2,3 -> 2,3
    const int lane = tid & 63;
    const int wv   = tid >> 6;
    const int sA   = sh * 2;       // first sub of this thread's pair

    // Build x-offset LUT: lutX[r] = byte offset of x[.][n][p+kh][q+kw][0].
    for (int e = tid; e < R_; e += 256) {
        const int n = e / 9, rem = e - n * 9;
        const int kh = rem / 3, kw = rem - kh * 3;
        lutX[e] = ((n * H_ + (p + kh)) * H_ + (q + kw)) * (CIN * 4);
    }

    // Wave-uniform x bases for the two subs of this thread's pair.
    const char* xbA = (const char*)(x + (size_t)(b0 + sA)     * XSUB);
    const char* xbB = (const char*)(x + (size_t)(b0 + sA + 1) * XSUB);
    const float4* rwcF4 = (const float4*)(rw + (size_t)c * R_ * CIN * COUT);

    auto stage = [&](int k, int buf) {
        // slot s = t*256+tid -> [ii=s>>7][wcr=(s>>2)&31][wog=s&3];
        // global f4 = wcr*32 + ii*4 + wog (chunk base k*1024 f4)
        const float4* gchunk = rwcF4 + (size_t)k * (CH * 32);
        #pragma unroll
        for (int t = 0; t < 4; ++t) {
            const int s   = t * 256 + tid;
            const int ii  = s >> 7;
            const int wcr = (s >> 2) & 31;
            async_copy16(gchunk + (wcr * 32 + ii * 4 + (s & 3)),
                         (char*)&wbuf[buf][0] + (t * 256 + (tid & 192)) * 16);
        }
    };

    __syncthreads();               // lutX visible

    int vofs[NCH];                 // this thread's 9 x byte-offsets (r = k*32+cr)
    #pragma unroll
    for (int k = 0; k < NCH; ++k) vofs[k] = lutX[k * CH + cr];

    float4 xa[2][2], xb[2][2];     // [slot][half]: subs sA / sA+1, 8 floats each
    auto xload = [&](int k, int s) {
        const char* a = xbA + vofs[k];
        const char* b = xbB + vofs[k];
        xa[s][0] = *(const float4*)(a);
        xa[s][1] = *(const float4*)(a + 16);
        xb[s][0] = *(const float4*)(b);
        xb[s][1] = *(const float4*)(b + 16);
    };

    float4 acc[NCH][2];

    stage(0, 0);
    xload(0, 0);
    #pragma unroll
    for (int k = 0; k < NCH; ++k) {
        __syncthreads();               // stage(k)+xload(k) drained; other buf free
        if (k + 1 < NCH) { stage(k + 1, (k + 1) & 1); xload(k + 1, (k + 1) & 1); }
        const float4 xA0 = xa[k & 1][0], xA1 = xa[k & 1][1];
        const float4 xB0 = xb[k & 1][0], xB1 = xb[k & 1][1];
        const float4* wb = &wbuf[k & 1][0];
        float4 a0 = make_float4(0.f, 0.f, 0.f, 0.f);
        float4 a1 = make_float4(0.f, 0.f, 0.f, 0.f);
        #define PRI_STEP(I, FA, FB) {                                   \
            const float4 wv4 = wb[(I) * 128 + cr * 4 + og];             \
            a0.x = fmaf(FA, wv4.x, a0.x);  a1.x = fmaf(FB, wv4.x, a1.x);\
            a0.y = fmaf(FA, wv4.y, a0.y);  a1.y = fmaf(FB, wv4.y, a1.y);\
            a0.z = fmaf(FA, wv4.z, a0.z);  a1.z = fmaf(FB, wv4.z, a1.z);\
            a0.w = fmaf(FA, wv4.w, a0.w);  a1.w = fmaf(FB, wv4.w, a1.w);}
        PRI_STEP(0, xA0.x, xB0.x)
        PRI_STEP(1, xA0.y, xB0.y)
        PRI_STEP(2, xA0.z, xB0.z)
        PRI_STEP(3, xA0.w, xB0.w)
        PRI_STEP(4, xA1.x, xB1.x)
        PRI_STEP(5, xA1.y, xB1.y)
        PRI_STEP(6, xA1.z, xB1.z)
        PRI_STEP(7, xA1.w, xB1.w)
        #undef PRI_STEP
        acc[k][0] = a0;  acc[k][1] = a1;
    }

    float lgA[NCH], lgB[NCH];
    #pragma unroll
    for (int j = 0; j < NCH; ++j) { lgA[j] = 0.f; lgB[j] = 0.f; }

    float4 v0, v1;   // squash output for subs sA, sA+1, couts og*4..og*4+3

    for (int it = 0; it < NITER; ++it) {
        const int par = it & 1;
        float4 s0 = make_float4(0.f, 0.f, 0.f, 0.f);
        float4 s1 = make_float4(0.f, 0.f, 0.f, 0.f);
        float se0 = 0.f, se1 = 0.f;

        if (it == 0) {
            #pragma unroll
            for (int j = 0; j < NCH; ++j) {
                s0.x += acc[j][0].x;  s1.x += acc[j][1].x;
                s0.y += acc[j][0].y;  s1.y += acc[j][1].y;
                s0.z += acc[j][0].z;  s1.z += acc[j][1].z;
                s0.w += acc[j][0].w;  s1.w += acc[j][1].w;
            }
        } else {
            #pragma unroll
            for (int j = 0; j < NCH; ++j) {
                float d0 = dot4(acc[j][0], v0);
                float d1 = dot4(acc[j][1], v1);
                d0 = dpp_add_xor1(d0);  d1 = dpp_add_xor1(d1);   // VALU
                d0 = dpp_add_xor2(d0);  d1 = dpp_add_xor2(d1);
                lgA[j] += d0;                 lgB[j] += d1;
                const float e0 = __expf(lgA[j]);
                const float e1 = __expf(lgB[j]);
                se0 += e0;                    se1 += e1;
                s0.x = fmaf(e0, acc[j][0].x, s0.x);  s1.x = fmaf(e1, acc[j][1].x, s1.x);
                s0.y = fmaf(e0, acc[j][0].y, s0.y);  s1.y = fmaf(e1, acc[j][1].y, s1.y);
                s0.z = fmaf(e0, acc[j][0].z, s0.z);  s1.z = fmaf(e1, acc[j][1].z, s1.z);
                s0.w = fmaf(e0, acc[j][0].w, s0.w);  s1.w = fmaf(e1, acc[j][1].w, s1.w);
            }
            // se: og-redundant; lane bits 2-3 on DPP, 4-5 on swizzle
            se0 = dpp_add_shr4(se0);  se1 = dpp_add_shr4(se1);
            se0 = dpp_add_shr8(se0);  se1 = dpp_add_shr8(se1);
            se0 += __shfl_xor(se0, 16, 64);  se1 += __shfl_xor(se1, 16, 64);
            se0 += __shfl_xor(se0, 32, 64);  se1 += __shfl_xor(se1, 32, 64);
            if (lane == 15) { redE[par][wv][0] = se0; redE[par][wv][1] = se1; }
        }

        // s-reduce over the wave's 16 cr-slots: bits 2-3 via DPP row_shr
        // (og-preserving; totals in lanes 12..15), bits 4-5 via swizzle.
        s0.x = dpp_add_shr4(s0.x);  s1.x = dpp_add_shr4(s1.x);
        s0.y = dpp_add_shr4(s0.y);  s1.y = dpp_add_shr4(s1.y);
        s0.z = dpp_add_shr4(s0.z);  s1.z = dpp_add_shr4(s1.z);
        s0.w = dpp_add_shr4(s0.w);  s1.w = dpp_add_shr4(s1.w);
        s0.x = dpp_add_shr8(s0.x);  s1.x = dpp_add_shr8(s1.x);
        s0.y = dpp_add_shr8(s0.y);  s1.y = dpp_add_shr8(s1.y);
        s0.z = dpp_add_shr8(s0.z);  s1.z = dpp_add_shr8(s1.z);
        s0.w = dpp_add_shr8(s0.w);  s1.w = dpp_add_shr8(s1.w);
        #pragma unroll
        for (int off = 16; off <= 32; off <<= 1) {
            s0.x += __shfl_xor(s0.x, off, 64);  s1.x += __shfl_xor(s1.x, off, 64);
            s0.y += __shfl_xor(s0.y, off, 64);  s1.y += __shfl_xor(s1.y, off, 64);
            s0.z += __shfl_xor(s0.z, off, 64);  s1.z += __shfl_xor(s1.z, off, 64);
            s0.w += __shfl_xor(s0.w, off, 64);  s1.w += __shfl_xor(s1.w, off, 64);
        }
        if (lane >= 12 && lane < 16) {   // lanes 12..15, og = lane&3
            *(float4*)&sRed[par][wv][0][(lane & 3) * 4] = s0;
            *(float4*)&sRed[par][wv][1][(lane & 3) * 4] = s1;
        }
        __syncthreads();

        // ---- all-wave redundant squash (R15): every thread computes its
        // own og-quad of v for subs sA, sA+1 (no divergent phase, no vS).
        const float4 pa0 = *(const float4*)&sRed[par][sh * 2    ][0][og * 4];
        const float4 pb0 = *(const float4*)&sRed[par][sh * 2 + 1][0][og * 4];
        const float4 pa1 = *(const float4*)&sRed[par][sh * 2    ][1][og * 4];
        const float4 pb1 = *(const float4*)&sRed[par][sh * 2 + 1][1][og * 4];
        float inv0, inv1;
        if (it == 0) {
            inv0 = inv1 = 1.0f / (float)R_;
        } else {
            inv0 = 1.0f / (redE[par][sh * 2][0] + redE[par][sh * 2 + 1][0]);
            inv1 = 1.0f / (redE[par][sh * 2][1] + redE[par][sh * 2 + 1][1]);
        }
        float4 sc0, sc1;
        sc0.x = (pa0.x + pb0.x) * inv0;  sc1.x = (pa1.x + pb1.x) * inv1;
        sc0.y = (pa0.y + pb0.y) * inv0;  sc1.y = (pa1.y + pb1.y) * inv1;
        sc0.z = (pa0.z + pb0.z) * inv0;  sc1.z = (pa1.z + pb1.z) * inv1;
        sc0.w = (pa0.w + pb0.w) * inv0;  sc1.w = (pa1.w + pb1.w) * inv1;
        float sn0 = dot4(sc0, sc0);
        float sn1 = dot4(sc1, sc1);
        sn0 = dpp_add_xor1(sn0);  sn1 = dpp_add_xor1(sn1);   // sum over og quad
        sn0 = dpp_add_xor2(sn0);  sn1 = dpp_add_xor2(sn1);
        const float f0 = sqrtf(sn0) / (1.0f + sn0);
        const float f1 = sqrtf(sn1) / (1.0f + sn1);
        v0.x = sc0.x * f0;  v1.x = sc1.x * f1;
        v0.y = sc0.y * f0;  v1.y = sc1.y * f1;
        v0.z = sc0.z * f0;  v1.z = sc1.z * f1;
        v0.w = sc0.w * f0;  v1.w = sc1.w * f1;
        // Next iter writes sRed/redE[!par]; the par-buffer overwrite (it+2)
        // sits behind it+1's barrier.
    }

    if (cr == 0) {   // 8 writer threads: (sh 0..1) x (og 0..3), 2 subs each
        *(float4*)&out[((((size_t)(b0 + sA)     * C_ + c) * W_ + p) * W_ + q) * COUT + og * 4] = v0;
        *(float4*)&out[((((size_t)(b0 + sA + 1) * C_ + c) * W_ + p) * W_ + q) * COUT + og * 4] = v1;
    }
}

extern "C" void kernel_launch(void* const* d_in, const int* in_sizes, int n_in,
                              void* d_out, int out_size, void* d_ws, size_t ws_size,
                              hipStream_t stream) {
    const float* x  = (const float*)d_in[0];
    const float* rw = (const float*)d_in[1];
    float* out = (float*)d_out;
    caps_routeC<<<dim3(W_ * W_ * 2 * C_), 256, 0, stream>>>(x, rw, out);
}

// Round 7
// 200.286 us; speedup vs baseline: 1.1264x; 1.1264x over previous
//
#include <hip/hip_runtime.h>
#include <math.h>

namespace {
constexpr int NIN   = 32;
constexpr int H_    = 14;
constexpr int CIN   = 8;
constexpr int C_    = 32;
constexpr int COUT  = 16;
constexpr int R_    = 288;
constexpr int W_    = 12;
constexpr int NITER = 3;
constexpr int CH    = 32;              // r per chunk
constexpr int NCH   = 9;               // 288/32
constexpr size_t XSUB = (size_t)NIN * H_ * H_ * CIN;   // x stride per batch elem
}

typedef unsigned int u32;
typedef const __attribute__((address_space(1))) u32* as1_u32p;
typedef __attribute__((address_space(3))) u32* as3_u32p;

__device__ __forceinline__ void async_copy16(const void* g, void* l) {
    __builtin_amdgcn_global_load_lds((as1_u32p)g, (as3_u32p)l, 16, 0, 0);
}
__device__ __forceinline__ float dot4(const float4 a, const float4 b) {
    return fmaf(a.x, b.x, fmaf(a.y, b.y, fmaf(a.z, b.z, a.w * b.w)));
}
// VALU-pipe cross-lane ops (DPP) — keep traffic off the DS pipe.
__device__ __forceinline__ float dpp_add_xor1(float v) {
    int t = __builtin_amdgcn_update_dpp(0, __float_as_int(v), 0xB1, 0xF, 0xF, true);
    return v + __int_as_float(t);
}
__device__ __forceinline__ float dpp_add_xor2(float v) {
    int t = __builtin_amdgcn_update_dpp(0, __float_as_int(v), 0x4E, 0xF, 0xF, true);
    return v + __int_as_float(t);
}
__device__ __forceinline__ float dpp_add_shr4(float v) {
    int t = __builtin_amdgcn_update_dpp(0, __float_as_int(v), 0x114, 0xF, 0xF, true);
    return v + __int_as_float(t);
}
__device__ __forceinline__ float dpp_add_shr8(float v) {
    int t = __builtin_amdgcn_update_dpp(0, __float_as_int(v), 0x118, 0xF, 0xF, true);
    return v + __int_as_float(t);
}

// R19 = R18's x-path diet at R17's 4-block residency.
// R18 post-mortem: lutX (+1 KB LDS) crossed the empirical 4-block LDS
// threshold (<=34304 B), dropping residency 10.1 -> 6.9 waves/CU; but
// per-resident-wave throughput IMPROVED ~25% (189x6.9 vs 161x10.1
// wave-us) — the instruction diet works. Fix: compute the 9 per-thread
// x offsets in REGISTERS at the prologue (9 const-div chains, one-time
// ~60 VALU ops) — no LDS LUT, LDS back to 34304 B.
// Structure otherwise identical to R18:
//  * XCD swizzle (R17): FETCH 24.5 -> 7.9 MB, keep.
//  * x-direct loads: 4 global_load_dwordx4 per thread per chunk from
//    wave-uniform bases (x is L2-resident post-swizzle); no DPP exchange.
//  * W via zero-VGPR global_load_lds double-buffer + plain __syncthreads
//    (counted-vmcnt 0-for-3: R14/R16).
//  * all-wave redundant squash epilogue (R15), parity-double-buffered.
// Lessons: 256-thr blocks (R6/R10); no forced waves/EU (R4); priors fp32
// (R2); LDS <= 34304 B hard cap for 4-block residency (R12/R17 vs
// R14/R16/R18); VGPR>=72 pins wave cap at 16/CU (R13-R16).
__global__ __launch_bounds__(256)
void caps_routeC(const float* __restrict__ x,
                 const float* __restrict__ rw,
                 float* __restrict__ out)
{
    const int tid = threadIdx.x;
    // XCD-aware decode (R17): xcd = hw%8; XCD k owns groups 8k..8k+7.
    const int hw    = blockIdx.x;
    const int xcd   = hw & 7;
    const int local = hw >> 3;          // 0..1151
    const int pq    = local % 144;
    const int gl    = local / 144;      // 0..7
    const int grp   = xcd * 8 + gl;     // = y*32 + c
    const int yb    = grp >> 5;         // batch-quad index 0..1
    const int c     = grp & 31;
    const int p  = pq / W_;
    const int q  = pq % W_;
    const int b0 = yb * 4;

    __shared__ float4 wbuf[2][1024];     // [buf][i(8)][cr(32)][og(4)] 16 KB each
    __shared__ float  sRed[2][4][2][16]; // [parity][wave][local sub][o]
    __shared__ float  redE[2][4][2];     // [parity][wave][local sub]

    const int og   = tid & 3;
    const int rl   = tid >> 2;     // 0..63
    const int cr   = rl & 31;      // chunk-local r
    const int sh   = rl >> 5;      // wave-uniform: waves 0,1 -> subs 0,1; 2,3 -> 2,3
    const int lane = tid & 63;
    const int wv   = tid >> 6;
    const int sA   = sh * 2;       // first sub of this thread's pair

    // Wave-uniform x bases for the two subs of this thread's pair.
    const char* xbA = (const char*)(x + (size_t)(b0 + sA)     * XSUB);
    const char* xbB = (const char*)(x + (size_t)(b0 + sA + 1) * XSUB);
    const float4* rwcF4 = (const float4*)(rw + (size_t)c * R_ * CIN * COUT);

    // Per-thread x byte-offsets for r = k*32 + cr, k = 0..8 — registers
    // only (R18's LDS LUT broke the 4-block residency threshold).
    int vofs[NCH];
    #pragma unroll
    for (int k = 0; k < NCH; ++k) {
        const int r  = k * CH + cr;
        const int n  = r / 9, rem = r - n * 9;
        const int kh = rem / 3, kw = rem - kh * 3;
        vofs[k] = ((n * H_ + (p + kh)) * H_ + (q + kw)) * (CIN * 4);
    }

    auto stage = [&](int k, int buf) {
        // slot s = t*256+tid -> [ii=s>>7][wcr=(s>>2)&31][wog=s&3];
        // global f4 = wcr*32 + ii*4 + wog (chunk base k*1024 f4)
        const float4* gchunk = rwcF4 + (size_t)k * (CH * 32);
        #pragma unroll
        for (int t = 0; t < 4; ++t) {
            const int s   = t * 256 + tid;
            const int ii  = s >> 7;
            const int wcr = (s >> 2) & 31;
            async_copy16(gchunk + (wcr * 32 + ii * 4 + (s & 3)),
                         (char*)&wbuf[buf][0] + (t * 256 + (tid & 192)) * 16);
        }
    };

    float4 xa[2][2], xb[2][2];     // [slot][half]: subs sA / sA+1, 8 floats each
    auto xload = [&](int k, int s) {
        const char* a = xbA + vofs[k];
        const char* b = xbB + vofs[k];
        xa[s][0] = *(const float4*)(a);
        xa[s][1] = *(const float4*)(a + 16);
        xb[s][0] = *(const float4*)(b);
        xb[s][1] = *(const float4*)(b + 16);
    };

    float4 acc[NCH][2];

    stage(0, 0);
    xload(0, 0);
    #pragma unroll
    for (int k = 0; k < NCH; ++k) {
        __syncthreads();               // stage(k)+xload(k) drained; other buf free
        if (k + 1 < NCH) { stage(k + 1, (k + 1) & 1); xload(k + 1, (k + 1) & 1); }
        const float4 xA0 = xa[k & 1][0], xA1 = xa[k & 1][1];
        const float4 xB0 = xb[k & 1][0], xB1 = xb[k & 1][1];
        const float4* wb = &wbuf[k & 1][0];
        float4 a0 = make_float4(0.f, 0.f, 0.f, 0.f);
        float4 a1 = make_float4(0.f, 0.f, 0.f, 0.f);
        #define PRI_STEP(I, FA, FB) {                                   \
            const float4 wv4 = wb[(I) * 128 + cr * 4 + og];             \
            a0.x = fmaf(FA, wv4.x, a0.x);  a1.x = fmaf(FB, wv4.x, a1.x);\
            a0.y = fmaf(FA, wv4.y, a0.y);  a1.y = fmaf(FB, wv4.y, a1.y);\
            a0.z = fmaf(FA, wv4.z, a0.z);  a1.z = fmaf(FB, wv4.z, a1.z);\
            a0.w = fmaf(FA, wv4.w, a0.w);  a1.w = fmaf(FB, wv4.w, a1.w);}
        PRI_STEP(0, xA0.x, xB0.x)
        PRI_STEP(1, xA0.y, xB0.y)
        PRI_STEP(2, xA0.z, xB0.z)
        PRI_STEP(3, xA0.w, xB0.w)
        PRI_STEP(4, xA1.x, xB1.x)
        PRI_STEP(5, xA1.y, xB1.y)
        PRI_STEP(6, xA1.z, xB1.z)
        PRI_STEP(7, xA1.w, xB1.w)
        #undef PRI_STEP
        acc[k][0] = a0;  acc[k][1] = a1;
    }

    float lgA[NCH], lgB[NCH];
    #pragma unroll
    for (int j = 0; j < NCH; ++j) { lgA[j] = 0.f; lgB[j] = 0.f; }

    float4 v0, v1;   // squash output for subs sA, sA+1, couts og*4..og*4+3

    for (int it = 0; it < NITER; ++it) {
        const int par = it & 1;
        float4 s0 = make_float4(0.f, 0.f, 0.f, 0.f);
        float4 s1 = make_float4(0.f, 0.f, 0.f, 0.f);
        float se0 = 0.f, se1 = 0.f;

        if (it == 0) {
            #pragma unroll
            for (int j = 0; j < NCH; ++j) {
                s0.x += acc[j][0].x;  s1.x += acc[j][1].x;
                s0.y += acc[j][0].y;  s1.y += acc[j][1].y;
                s0.z += acc[j][0].z;  s1.z += acc[j][1].z;
                s0.w += acc[j][0].w;  s1.w += acc[j][1].w;
            }
        } else {
            #pragma unroll
            for (int j = 0; j < NCH; ++j) {
                float d0 = dot4(acc[j][0], v0);
                float d1 = dot4(acc[j][1], v1);
                d0 = dpp_add_xor1(d0);  d1 = dpp_add_xor1(d1);   // VALU
                d0 = dpp_add_xor2(d0);  d1 = dpp_add_xor2(d1);
                lgA[j] += d0;                 lgB[j] += d1;
                const float e0 = __expf(lgA[j]);
                const float e1 = __expf(lgB[j]);
                se0 += e0;                    se1 += e1;
                s0.x = fmaf(e0, acc[j][0].x, s0.x);  s1.x = fmaf(e1, acc[j][1].x, s1.x);
                s0.y = fmaf(e0, acc[j][0].y, s0.y);  s1.y = fmaf(e1, acc[j][1].y, s1.y);
                s0.z = fmaf(e0, acc[j][0].z, s0.z);  s1.z = fmaf(e1, acc[j][1].z, s1.z);
                s0.w = fmaf(e0, acc[j][0].w, s0.w);  s1.w = fmaf(e1, acc[j][1].w, s1.w);
            }
            // se: og-redundant; lane bits 2-3 on DPP, 4-5 on swizzle
            se0 = dpp_add_shr4(se0);  se1 = dpp_add_shr4(se1);
            se0 = dpp_add_shr8(se0);  se1 = dpp_add_shr8(se1);
            se0 += __shfl_xor(se0, 16, 64);  se1 += __shfl_xor(se1, 16, 64);
            se0 += __shfl_xor(se0, 32, 64);  se1 += __shfl_xor(se1, 32, 64);
            if (lane == 15) { redE[par][wv][0] = se0; redE[par][wv][1] = se1; }
        }

        // s-reduce over the wave's 16 cr-slots: bits 2-3 via DPP row_shr
        // (og-preserving; totals in lanes 12..15), bits 4-5 via swizzle.
        s0.x = dpp_add_shr4(s0.x);  s1.x = dpp_add_shr4(s1.x);
        s0.y = dpp_add_shr4(s0.y);  s1.y = dpp_add_shr4(s1.y);
        s0.z = dpp_add_shr4(s0.z);  s1.z = dpp_add_shr4(s1.z);
        s0.w = dpp_add_shr4(s0.w);  s1.w = dpp_add_shr4(s1.w);
        s0.x = dpp_add_shr8(s0.x);  s1.x = dpp_add_shr8(s1.x);
        s0.y = dpp_add_shr8(s0.y);  s1.y = dpp_add_shr8(s1.y);
        s0.z = dpp_add_shr8(s0.z);  s1.z = dpp_add_shr8(s1.z);
        s0.w = dpp_add_shr8(s0.w);  s1.w = dpp_add_shr8(s1.w);
        #pragma unroll
        for (int off = 16; off <= 32; off <<= 1) {
            s0.x += __shfl_xor(s0.x, off, 64);  s1.x += __shfl_xor(s1.x, off, 64);
            s0.y += __shfl_xor(s0.y, off, 64);  s1.y += __shfl_xor(s1.y, off, 64);
            s0.z += __shfl_xor(s0.z, off, 64);  s1.z += __shfl_xor(s1.z, off, 64);
            s0.w += __shfl_xor(s0.w, off, 64);  s1.w += __shfl_xor(s1.w, off, 64);
        }
        if (lane >= 12 && lane < 16) {   // lanes 12..15, og = lane&3
            *(float4*)&sRed[par][wv][0][(lane & 3) * 4] = s0;
            *(float4*)&sRed[par][wv][1][(lane & 3) * 4] = s1;
        }
        __syncthreads();

        // ---- all-wave redundant squash (R15): every thread computes its
        // own og-quad of v for subs sA, sA+1 (no divergent phase, no vS).
        const float4 pa0 = *(const float4*)&sRed[par][sh * 2    ][0][og * 4];
        const float4 pb0 = *(const float4*)&sRed[par][sh * 2 + 1][0][og * 4];
        const float4 pa1 = *(const float4*)&sRed[par][sh * 2    ][1][og * 4];
        const float4 pb1 = *(const float4*)&sRed[par][sh * 2 + 1][1][og * 4];
        float inv0, inv1;
        if (it == 0) {
            inv0 = inv1 = 1.0f / (float)R_;
        } else {
            inv0 = 1.0f / (redE[par][sh * 2][0] + redE[par][sh * 2 + 1][0]);
            inv1 = 1.0f / (redE[par][sh * 2][1] + redE[par][sh * 2 + 1][1]);
        }
        float4 sc0, sc1;
        sc0.x = (pa0.x + pb0.x) * inv0;  sc1.x = (pa1.x + pb1.x) * inv1;
        sc0.y = (pa0.y + pb0.y) * inv0;  sc1.y = (pa1.y + pb1.y) * inv1;
        sc0.z = (pa0.z + pb0.z) * inv0;  sc1.z = (pa1.z + pb1.z) * inv1;
        sc0.w = (pa0.w + pb0.w) * inv0;  sc1.w = (pa1.w + pb1.w) * inv1;
        float sn0 = dot4(sc0, sc0);
        float sn1 = dot4(sc1, sc1);
        sn0 = dpp_add_xor1(sn0);  sn1 = dpp_add_xor1(sn1);   // sum over og quad
        sn0 = dpp_add_xor2(sn0);  sn1 = dpp_add_xor2(sn1);
        const float f0 = sqrtf(sn0) / (1.0f + sn0);
        const float f1 = sqrtf(sn1) / (1.0f + sn1);
        v0.x = sc0.x * f0;  v1.x = sc1.x * f1;
        v0.y = sc0.y * f0;  v1.y = sc1.y * f1;
        v0.z = sc0.z * f0;  v1.z = sc1.z * f1;
        v0.w = sc0.w * f0;  v1.w = sc1.w * f1;
        // Next iter writes sRed/redE[!par]; the par-buffer overwrite (it+2)
        // sits behind it+1's barrier.
    }

    if (cr == 0) {   // 8 writer threads: (sh 0..1) x (og 0..3), 2 subs each
        *(float4*)&out[((((size_t)(b0 + sA)     * C_ + c) * W_ + p) * W_ + q) * COUT + og * 4] = v0;
        *(float4*)&out[((((size_t)(b0 + sA + 1) * C_ + c) * W_ + p) * W_ + q) * COUT + og * 4] = v1;
    }
}

extern "C" void kernel_launch(void* const* d_in, const int* in_sizes, int n_in,
                              void* d_out, int out_size, void* d_ws, size_t ws_size,
                              hipStream_t stream) {
    const float* x  = (const float*)d_in[0];
    const float* rw = (const float*)d_in[1];
    float* out = (float*)d_out;
    caps_routeC<<<dim3(W_ * W_ * 2 * C_), 256, 0, stream>>>(x, rw, out);
}